// Round 2
// baseline (141.656 us; speedup 1.0000x reference)
//
#include <hip/hip_runtime.h>

#define T_LEN 4096
#define D_IN 128
#define U_H 256
#define REC_MAXV 0.0625f

typedef __attribute__((ext_vector_type(8))) short short8;
typedef __attribute__((ext_vector_type(4))) float f32x4;

__device__ __forceinline__ short f2bf(float f) {
    unsigned u = __builtin_bit_cast(unsigned, f);
    unsigned r = u + 0x7FFFu + ((u >> 16) & 1u);
    return (short)(r >> 16);
}

// ---------------- kernel 0: h[b][u] = relu(xs[b,T-1,:] . We[u,:] + be[u]) ----
__global__ void k_h(const float* __restrict__ xs, const float* __restrict__ We,
                    const float* __restrict__ be, float* __restrict__ h) {
    int b = blockIdx.x, u = threadIdx.x;
    const f32x4* xr = (const f32x4*)(xs + ((size_t)b * T_LEN + (T_LEN - 1)) * D_IN);
    const f32x4* wr = (const f32x4*)(We + (size_t)u * D_IN);
    float s = 0.f;
#pragma unroll
    for (int i = 0; i < 32; ++i) {
        f32x4 a = xr[i], w = wr[i];
        s += a[0]*w[0] + a[1]*w[1] + a[2]*w[2] + a[3]*w[3];
    }
    s += be[u];
    h[b * U_H + u] = fmaxf(s, 0.f);
}

// ---------------- kernel 1: prep bud, weight fragments, zero loss ------------
// WdF frag (k=K/32 step 0..3, ut=u-tile 0..15): lane l elem j =
//   Wd[ut*16+(l&15)][k*32+8*(l>>4)+j]   (B-operand layout for 16x16x32 mfma)
// WoF frag (k2 0..7, dt 0..7): lane l elem j = Wo[dt*16+(l&15)][k2*32+8*(l>>4)+j]
__global__ void k_prep(const float* __restrict__ Wd, const float* __restrict__ Wo,
                       const float* __restrict__ bd, const float* __restrict__ ud,
                       const float* __restrict__ hbuf, float* __restrict__ bud,
                       short* __restrict__ WdF, short* __restrict__ WoF,
                       float* __restrict__ loss) {
    int gid = blockIdx.x * 256 + threadIdx.x;   // 0..16383
    int u = gid & 255;
    float udc = fminf(fmaxf(ud[u], -REC_MAXV), REC_MAXV);
    bud[gid] = bd[u] + udc * hbuf[gid];
    if (gid == 0) *loss = 0.f;

    if (gid < 4096) {
        int frag = gid >> 6, lane = gid & 63;
        int k = frag >> 4, ut = frag & 15;
        int l15 = lane & 15, hg = lane >> 4;
        const float* src = Wd + (size_t)(ut * 16 + l15) * D_IN + k * 32 + hg * 8;
        short8 v;
#pragma unroll
        for (int j = 0; j < 8; ++j) v[j] = f2bf(src[j]);
        *(short8*)(WdF + (size_t)gid * 8) = v;
    } else if (gid < 8192) {
        int g2 = gid - 4096;
        int frag = g2 >> 6, lane = g2 & 63;
        int k2 = frag >> 3, dt = frag & 7;
        int l15 = lane & 15, hg = lane >> 4;
        const float* src = Wo + (size_t)(dt * 16 + l15) * U_H + k2 * 32 + hg * 8;
        short8 v;
#pragma unroll
        for (int j = 0; j < 8; ++j) v[j] = f2bf(src[j]);
        *(short8*)(WoF + (size_t)g2 * 8) = v;
    }
}

// ---------------- kernel 2: t=0 loss term ------------------------------------
__global__ void k_loss0(const float* __restrict__ xs, const float* __restrict__ hbuf,
                        const float* __restrict__ Wo, const float* __restrict__ bo,
                        float* __restrict__ loss) {
    int b = blockIdx.x, d = threadIdx.x;   // 128 threads
    const f32x4* hr = (const f32x4*)(hbuf + b * U_H);
    const f32x4* wr = (const f32x4*)(Wo + (size_t)d * U_H);
    float s = 0.f;
#pragma unroll
    for (int i = 0; i < 64; ++i) {
        f32x4 a = hr[i], w = wr[i];
        s += a[0]*w[0] + a[1]*w[1] + a[2]*w[2] + a[3]*w[3];
    }
    s += bo[d];
    float x = xs[((size_t)b * T_LEN + T_LEN - 1) * D_IN + d];
    float diff = x - s;
    float v = diff * diff;
#pragma unroll
    for (int o = 32; o > 0; o >>= 1) v += __shfl_down(v, o);
    if ((threadIdx.x & 63) == 0) atomicAdd(loss, v * (1.f / 262144.f));
}

// ---------------- kernel 3: main fused pipeline (restructured) ---------------
// 512 blocks x 512 threads (8 waves), 16 tiles of 32 rows per block.
// All 8 waves cooperate on one tile. Weights live in VGPRs:
//   wave w: GEMM1 u-slice [32w,32w+32)  (8 Wd frags), GEMM2 d-slice [16w,16w+16) (8 Wo frags).
// LDS: double-buffered X frags (bf16, 8KB each) + double-buffered dec (16KB each,
// XOR-swizzled (row&7)<<4 so b128 read-back is conflict-free).
__global__ __launch_bounds__(512, 4) void k_main(
        const float* __restrict__ xs, const float* __restrict__ bud,
        const float* __restrict__ bo, const short* __restrict__ WF,
        float* __restrict__ loss) {
    __shared__ __align__(16) char lds[49216];
    char* Xb0  = lds;
    char* Xb1  = lds + 8192;
    char* dec0 = lds + 16384;
    char* dec1 = lds + 32768;
    float* wsumf = (float*)(lds + 49152);

    const int tid = threadIdx.x;
    const int wave = tid >> 6, lane = tid & 63;
    const int l15 = lane & 15, hg = lane >> 4;

    // ---- weights -> VGPRs (16 x b128 global loads, L2-hot) ----
    const short* WdF = WF;
    const short* WoF = WF + 32768;
    short8 wdf[8], wof[8];
#pragma unroll
    for (int k = 0; k < 4; ++k)
#pragma unroll
        for (int h = 0; h < 2; ++h)
            wdf[k*2+h] = *(const short8*)(WdF + (size_t)((k*16 + wave*2 + h)*64 + lane)*8);
#pragma unroll
    for (int uc = 0; uc < 8; ++uc)
        wof[uc] = *(const short8*)(WoF + (size_t)((uc*8 + wave)*64 + lane)*8);

    const float bo_w = bo[wave*16 + l15];

    // staging role: this thread stages frag f=wave (mt=f>>2, k=f&3)
    const int smt = wave >> 2, sk = wave & 3;

    const int tile0 = blockIdx.x * 16;
    f32x4 pa, pb;
    {
        int b = tile0 >> 7, tt = (tile0 & 127) << 5;
        const float* p = xs + ((size_t)b << 19) + (size_t)(tt + smt*16 + l15)*128 + sk*32 + hg*8;
        pa = *(const f32x4*)p; pb = *(const f32x4*)(p + 4);
    }

    float lacc = 0.f;

    for (int it = 0; it < 16; ++it) {
        const int tcur = tile0 + it;
        const int b  = tcur >> 7;
        const int t0 = (tcur & 127) << 5;
        const float* xsb = xs + ((size_t)b << 19);

        char* xb  = (it & 1) ? Xb1 : Xb0;
        char* dcb = (it & 1) ? dec1 : dec0;

        // ---- phase A: convert prefetched rows, store A-frags; prefetch next ----
        {
            short8 a;
            a[0]=f2bf(pa[0]); a[1]=f2bf(pa[1]); a[2]=f2bf(pa[2]); a[3]=f2bf(pa[3]);
            a[4]=f2bf(pb[0]); a[5]=f2bf(pb[1]); a[6]=f2bf(pb[2]); a[7]=f2bf(pb[3]);
            *(short8*)(xb + tid*16) = a;
        }
        if (it < 15) {
            int tn = tcur + 1;
            int bn = tn >> 7, tt = (tn & 127) << 5;
            const float* p = xs + ((size_t)bn << 19) + (size_t)(tt + smt*16 + l15)*128 + sk*32 + hg*8;
            pa = *(const f32x4*)p; pb = *(const f32x4*)(p + 4);
        }
        __syncthreads();

        // ---- phase B: GEMM1, u-slice [32w,32w+32), relu -> dec LDS ----
        {
            const short8* xf = (const short8*)xb;
            f32x4 c1[2][2];
            c1[0][0]=(f32x4){0,0,0,0}; c1[0][1]=(f32x4){0,0,0,0};
            c1[1][0]=(f32x4){0,0,0,0}; c1[1][1]=(f32x4){0,0,0,0};
#pragma unroll
            for (int k = 0; k < 4; ++k) {
                short8 a0 = xf[k*64 + lane];          // mt=0, frag 0*4+k
                short8 a1 = xf[(4+k)*64 + lane];      // mt=1, frag 1*4+k
                c1[0][0] = __builtin_amdgcn_mfma_f32_16x16x32_bf16(a0, wdf[k*2+0], c1[0][0], 0,0,0);
                c1[0][1] = __builtin_amdgcn_mfma_f32_16x16x32_bf16(a0, wdf[k*2+1], c1[0][1], 0,0,0);
                c1[1][0] = __builtin_amdgcn_mfma_f32_16x16x32_bf16(a1, wdf[k*2+0], c1[1][0], 0,0,0);
                c1[1][1] = __builtin_amdgcn_mfma_f32_16x16x32_bf16(a1, wdf[k*2+1], c1[1][1], 0,0,0);
            }
            const float bud0 = bud[b*256 + wave*32 + l15];
            const float bud1 = bud[b*256 + wave*32 + 16 + l15];
#pragma unroll
            for (int mt = 0; mt < 2; ++mt)
#pragma unroll
                for (int j = 0; j < 4; ++j) {
                    int row = mt*16 + 4*hg + j;
                    int sw = (row & 7) << 4;
                    int off0 = (row << 9) + ((wave*32 + l15) << 1);
                    int off1 = (row << 9) + ((wave*32 + 16 + l15) << 1);
                    *(short*)(dcb + (off0 ^ sw)) = f2bf(fmaxf(c1[mt][0][j] + bud0, 0.f));
                    *(short*)(dcb + (off1 ^ sw)) = f2bf(fmaxf(c1[mt][1][j] + bud1, 0.f));
                }
        }
        __syncthreads();

        // ---- phase C: GEMM2 d-slice [16w,16w+16) + fused loss epilogue ----
        {
            f32x4 o0 = (f32x4){0,0,0,0}, o1 = (f32x4){0,0,0,0};
            const int sw = (l15 & 7) << 4;
#pragma unroll
            for (int uc = 0; uc < 8; ++uc) {
                int off0 = (l15 << 9) + uc*64 + hg*16;
                int off1 = ((16 + l15) << 9) + uc*64 + hg*16;
                short8 da0 = *(const short8*)(dcb + (off0 ^ sw));
                short8 da1 = *(const short8*)(dcb + (off1 ^ sw));
                o0 = __builtin_amdgcn_mfma_f32_16x16x32_bf16(da0, wof[uc], o0, 0,0,0);
                o1 = __builtin_amdgcn_mfma_f32_16x16x32_bf16(da1, wof[uc], o1, 0,0,0);
            }
            const int dcol = wave*16 + l15;
#pragma unroll
            for (int mt = 0; mt < 2; ++mt) {
#pragma unroll
                for (int j = 0; j < 4; ++j) {
                    int m = mt*16 + 4*hg + j;
                    int trow = t0 + m;
                    int mi = trow > 0 ? trow - 1 : 0;
                    float tgt = xsb[(size_t)mi * 128 + dcol];
                    float outv = (mt ? o1[j] : o0[j]) + bo_w;
                    float diff = tgt - outv;
                    lacc += trow > 0 ? diff * diff : 0.f;
                }
            }
        }
    }

    // ---- block-level loss reduction: 1 atomic per block ----
#pragma unroll
    for (int o = 32; o > 0; o >>= 1) lacc += __shfl_down(lacc, o);
    if (lane == 0) wsumf[wave] = lacc;
    __syncthreads();
    if (tid == 0) {
        float s = 0.f;
#pragma unroll
        for (int i = 0; i < 8; ++i) s += wsumf[i];
        atomicAdd(loss, s * (1.f / 262144.f));
    }
}

extern "C" void kernel_launch(void* const* d_in, const int* in_sizes, int n_in,
                              void* d_out, int out_size, void* d_ws, size_t ws_size,
                              hipStream_t stream) {
    const float* xs = (const float*)d_in[0];
    const float* We = (const float*)d_in[1];
    const float* be = (const float*)d_in[2];
    // d_in[3] = ue (unused: encoder hidden state is always zero)
    const float* Wd = (const float*)d_in[4];
    const float* bd = (const float*)d_in[5];
    const float* ud = (const float*)d_in[6];
    const float* Wo = (const float*)d_in[7];
    const float* bo = (const float*)d_in[8];
    float* loss = (float*)d_out;

    char* ws = (char*)d_ws;
    float* h   = (float*)(ws);              // 65536 B
    float* bud = (float*)(ws + 65536);      // 65536 B
    short* WF  = (short*)(ws + 131072);     // 131072 B (WdF then WoF)
    short* WdF = WF;
    short* WoF = WF + 32768;

    k_h<<<64, 256, 0, stream>>>(xs, We, be, h);
    k_prep<<<64, 256, 0, stream>>>(Wd, Wo, bd, ud, h, bud, WdF, WoF, loss);
    k_loss0<<<64, 128, 0, stream>>>(xs, h, Wo, bo, loss);
    k_main<<<512, 512, 0, stream>>>(xs, bud, bo, WF, loss);
}